// Round 2
// baseline (208.746 us; speedup 1.0000x reference)
//
#include <hip/hip_runtime.h>

typedef unsigned short u16;
typedef unsigned int   u32;
typedef __attribute__((ext_vector_type(8))) short short8;   // 8 bf16 = 4 VGPRs
typedef __attribute__((ext_vector_type(4))) short short4v;  // 4 bf16 = 2 VGPRs
typedef __attribute__((ext_vector_type(4))) float f32x4;

#define NB    4      // batch
#define NCH   256    // channels
#define NHD   8      // heads
#define HD    32     // head dim
#define NSP   2304   // H*W
#define NBH   32     // NB*NHD
#define NKT   36     // NSP/64 K-tiles

// round-to-nearest-even fp32 -> bf16 bits
__device__ __forceinline__ u16 f2bf(float f) {
    u32 u = __float_as_uint(f);
    u += 0x7FFFu + ((u >> 16) & 1u);
    return (u16)(u >> 16);
}
__device__ __forceinline__ u32 pack2(float a, float b) {
    return (u32)f2bf(a) | ((u32)f2bf(b) << 16);
}
// packed f32x2 -> bf16x2 (hw RNE if available)
__device__ __forceinline__ u32 pkbf(float a, float b) {
#if __has_builtin(__builtin_amdgcn_cvt_pk_bf16_f32)
    typedef __attribute__((ext_vector_type(2))) __bf16 bf16x2;
    bf16x2 r = __builtin_amdgcn_cvt_pk_bf16_f32(a, b);
    union { bf16x2 v; u32 u; } cv; cv.v = r; return cv.u;
#else
    return pack2(a, b);
#endif
}

// async global->LDS, 16B per lane; LDS dest = wave-uniform base + lane*16
#define GLOAD_LDS16(g, l) \
  __builtin_amdgcn_global_load_lds((const __attribute__((address_space(1))) void*)(g), \
                                   (__attribute__((address_space(3))) void*)(l), 16, 0, 0)

// ---------------- proj_w -> bf16 ----------------
__global__ __launch_bounds__(256) void wcast_kernel(const float* __restrict__ w,
                                                    u16* __restrict__ wb) {
    int i = blockIdx.x * 256 + threadIdx.x;          // 16384 float4 chunks
    float4 v = ((const float4*)w)[i];
    ((uint2*)wb)[i] = make_uint2(pack2(v.x, v.y), pack2(v.z, v.w));
}

// ---------------- normalize q,k (temp*log2e folded into q); cast v ----------------
__global__ __launch_bounds__(256) void prep_kernel(
    const float* __restrict__ qkv, const float* __restrict__ temp,
    u16* __restrict__ Qn, u16* __restrict__ Kn, u16* __restrict__ Vt)
{
    const int bh = blockIdx.y;
    const int b = bh >> 3, head = bh & 7;
    const int n = blockIdx.x * 256 + threadIdx.x;
    const float* qp = qkv + ((size_t)(b * 3 * NCH + head * HD)) * NSP + n;
    const float* kp = qp + (size_t)NCH * NSP;
    const float* vp = qp + (size_t)(2 * NCH) * NSP;

    float qv[HD], kv[HD];
    float qs = 0.f, ks = 0.f;
#pragma unroll
    for (int d = 0; d < HD; ++d) {
        qv[d] = qp[(size_t)d * NSP];
        kv[d] = kp[(size_t)d * NSP];
        qs += qv[d] * qv[d];
        ks += kv[d] * kv[d];
    }
    // fold temp * log2(e) into Q: exp(relu(s*t)) == exp2(relu(q'.k))  (t >= 0)
    const float tl2 = temp[head] * 1.44269504088896f;
    const float qsc = tl2 / fmaxf(sqrtf(qs), 1e-12f);
    const float ksc = 1.f / fmaxf(sqrtf(ks), 1e-12f);
    u32* qd = (u32*)(Qn + ((size_t)bh * NSP + n) * HD);
    u32* kd = (u32*)(Kn + ((size_t)bh * NSP + n) * HD);
#pragma unroll
    for (int i = 0; i < HD / 2; ++i) {
        qd[i] = pack2(qv[2 * i] * qsc, qv[2 * i + 1] * qsc);
        kd[i] = pack2(kv[2 * i] * ksc, kv[2 * i + 1] * ksc);
    }
    u16* vd = Vt + (size_t)bh * HD * NSP + n;
#pragma unroll
    for (int d = 0; d < HD; ++d)
        vd[(size_t)d * NSP] = f2bf(vp[(size_t)d * NSP]);
}

// ---------------- flash attention, S^T form: no P round-trip through LDS ----------------
// block = 128 thr (2 waves), grid (NSP/64, NBH). Wave owns 32 Q rows (2 q-tiles).
// S^T = K.Q  (C/D: col=qrow=l15, row=krow=quad*4+r) feeds PV directly as A-frag
// under k-permutation sigma(q*8+j) = q*4+j (j<4) | 16+q*4+j-4 (j>=4); V B-frags
// are read with the same sigma (two b64s from a 144B-padded V^T tile).
__global__ __launch_bounds__(128) void attn_kernel(
    const u16* __restrict__ Qn, const u16* __restrict__ Kn,
    const u16* __restrict__ Vt, u16* __restrict__ X)
{
    __shared__ u16 lds[2][4352];   // per buf: K 64x32 @ [0,2048) | Vpad 32 rows x 72 @ [2048,4352)
    const int bh = blockIdx.y, b = bh >> 3, head = bh & 7;
    const int t = threadIdx.x, w = t >> 6, lane = t & 63;
    const int l15 = lane & 15, quad = lane >> 4;
    const int qbase = blockIdx.x * 64 + w * 32;

    const u16* Kg = Kn + (size_t)bh * NSP * HD;   // (n, d) rows of 64B
    const u16* Vg = Vt + (size_t)bh * HD * NSP;   // (d, n)

    // Q B-frags (B[k=d][n=qrow]: n=l15, k=quad*8+j) — held all kernel
    short8 qfrag[2];
#pragma unroll
    for (int t2 = 0; t2 < 2; ++t2)
        qfrag[t2] = *(const short8*)(Qn + ((size_t)bh * NSP + qbase + t2 * 16 + l15) * HD + quad * 8);

    // V staging map: thread t covers row d = t>>2, 2x16B at n-offset (t&3)*16
    const int vd = t >> 2;
    const int vn0 = (t & 3) * 16;
    const u16* vsrc = Vg + (size_t)vd * NSP + vn0;

    f32x4 oacc[2][2] = {{{0,0,0,0},{0,0,0,0}},{{0,0,0,0},{0,0,0,0}}};
    float rs[2] = {0.f, 0.f};

    // prologue: stage tile 0 into buf 0
    GLOAD_LDS16(Kg + t * 8,        &lds[0][t * 8]);
    GLOAD_LDS16(Kg + 1024 + t * 8, &lds[0][1024 + t * 8]);
    {
        short8 v0 = *(const short8*)(vsrc);
        short8 v1 = *(const short8*)(vsrc + 8);
        *(short8*)&lds[0][2048 + vd * 72 + vn0]     = v0;
        *(short8*)&lds[0][2048 + vd * 72 + vn0 + 8] = v1;
    }
    __syncthreads();

    for (int kt = 0; kt < NKT; ++kt) {
        u16* buf  = lds[kt & 1];
        u16* nbuf = lds[(kt & 1) ^ 1];
        short8 v0, v1;
        if (kt < NKT - 1) {   // prefetch next tile into other buffer
            const u16* ks = Kg + (size_t)(kt + 1) * 2048;
            GLOAD_LDS16(ks + t * 8,        nbuf + t * 8);
            GLOAD_LDS16(ks + 1024 + t * 8, nbuf + 1024 + t * 8);
            v0 = *(const short8*)(vsrc + (kt + 1) * 64);
            v1 = *(const short8*)(vsrc + (kt + 1) * 64 + 8);
        }

        // K A-frags (A[m=krow]: m=l15, k=quad*8+j over d), shared by both q-tiles
        short8 ka[4];
#pragma unroll
        for (int i = 0; i < 4; ++i)
            ka[i] = *(const short8*)(buf + (i * 16 + l15) * HD + quad * 8);

        // V B-frags with sigma: lo4 = n c*32+quad*4+{0..3}, hi4 = +16; d col = l15+16h
        short8 vb[2][2];
#pragma unroll
        for (int c = 0; c < 2; ++c)
#pragma unroll
            for (int h = 0; h < 2; ++h) {
                const u16* p = buf + 2048 + (l15 + 16 * h) * 72 + c * 32 + quad * 4;
                short4v lo = *(const short4v*)(p);
                short4v hi = *(const short4v*)(p + 16);
                vb[c][h] = (short8){lo[0], lo[1], lo[2], lo[3], hi[0], hi[1], hi[2], hi[3]};
            }

#pragma unroll
        for (int t2 = 0; t2 < 2; ++t2) {
            f32x4 sf[4];
#pragma unroll
            for (int i = 0; i < 4; ++i)
                sf[i] = __builtin_amdgcn_mfma_f32_16x16x32_bf16(ka[i], qfrag[t2], (f32x4){0.f,0.f,0.f,0.f}, 0, 0, 0);
            float ev[4][4];
#pragma unroll
            for (int i = 0; i < 4; ++i)
#pragma unroll
                for (int r = 0; r < 4; ++r) {
                    float e = exp2f(fmaxf(sf[i][r], 0.f));
                    rs[t2] += e;
                    ev[i][r] = e;
                }
#pragma unroll
            for (int c = 0; c < 2; ++c) {
                union { short8 s; u32 u[4]; } pa;
                pa.u[0] = pkbf(ev[2*c][0],   ev[2*c][1]);
                pa.u[1] = pkbf(ev[2*c][2],   ev[2*c][3]);
                pa.u[2] = pkbf(ev[2*c+1][0], ev[2*c+1][1]);
                pa.u[3] = pkbf(ev[2*c+1][2], ev[2*c+1][3]);
#pragma unroll
                for (int h = 0; h < 2; ++h)
                    oacc[t2][h] = __builtin_amdgcn_mfma_f32_16x16x32_bf16(pa.s, vb[c][h], oacc[t2][h], 0, 0, 0);
            }
        }

        if (kt < NKT - 1) {   // V write into other buffer (vmcnt hidden by compute above)
            *(short8*)(nbuf + 2048 + vd * 72 + vn0)     = v0;
            *(short8*)(nbuf + 2048 + vd * 72 + vn0 + 8) = v1;
        }
        __syncthreads();
    }

    // rowsum lives per-lane at qrow = l15: reduce across quads only
#pragma unroll
    for (int m = 16; m < 64; m <<= 1) {
        rs[0] += __shfl_xor(rs[0], m, 64);
        rs[1] += __shfl_xor(rs[1], m, 64);
    }
    float inv[2][4];
#pragma unroll
    for (int t2 = 0; t2 < 2; ++t2)
#pragma unroll
        for (int r = 0; r < 4; ++r)
            inv[t2][r] = 1.f / __shfl(rs[t2], quad * 4 + r, 16);

    // X[b][n][head*32+d]
    u16* Xb = X + (size_t)b * NSP * NCH + head * HD;
#pragma unroll
    for (int t2 = 0; t2 < 2; ++t2)
#pragma unroll
        for (int r = 0; r < 4; ++r) {
            u16* row = Xb + (size_t)(qbase + t2 * 16 + quad * 4 + r) * NCH;
            row[l15]      = f2bf(oacc[t2][0][r] * inv[t2][r]);
            row[16 + l15] = f2bf(oacc[t2][1][r] * inv[t2][r]);
        }
}

// ---------------- 1x1 conv: out[b,o,n] = sum_c W[o,c] X[b,n,c] + bias[o] ----------------
__global__ __launch_bounds__(256) void proj_kernel(
    const u16* __restrict__ Wb, const u16* __restrict__ X,
    const float* __restrict__ bias, float* __restrict__ out)
{
    const int b = blockIdx.z;
    const int w = threadIdx.x >> 6, lane = threadIdx.x & 63;
    const int l15 = lane & 15, quad = lane >> 4;
    const int obase = blockIdx.y * 64 + w * 16;
    const int nbase = blockIdx.x * 64;

    const u16* wrow = Wb + (size_t)(obase + l15) * NCH + quad * 8;
    const u16* xrow = X + ((size_t)b * NSP + nbase + l15) * NCH + quad * 8;

    f32x4 acc[4] = {{0,0,0,0},{0,0,0,0},{0,0,0,0},{0,0,0,0}};
#pragma unroll
    for (int ks = 0; ks < 8; ++ks) {
        const short8 af = *(const short8*)(wrow + ks * 32);
#pragma unroll
        for (int jn = 0; jn < 4; ++jn) {
            const short8 bf = *(const short8*)(xrow + (size_t)jn * 16 * NCH + ks * 32);
            acc[jn] = __builtin_amdgcn_mfma_f32_16x16x32_bf16(af, bf, acc[jn], 0, 0, 0);
        }
    }
#pragma unroll
    for (int r = 0; r < 4; ++r) {
        const int o = obase + quad * 4 + r;
        const float bo = bias[o];
        float* orow = out + ((size_t)b * NCH + o) * NSP + nbase;
#pragma unroll
        for (int jn = 0; jn < 4; ++jn)
            orow[jn * 16 + l15] = acc[jn][r] + bo;
    }
}

extern "C" void kernel_launch(void* const* d_in, const int* in_sizes, int n_in,
                              void* d_out, int out_size, void* d_ws, size_t ws_size,
                              hipStream_t stream) {
    const float* qkv   = (const float*)d_in[0];
    const float* temp  = (const float*)d_in[1];   // 8 head temps
    const float* projw = (const float*)d_in[2];
    const float* projb = (const float*)d_in[3];
    float* out = (float*)d_out;

    // workspace: Qn | Kn | Vt | X (each 2,359,296 bf16) | Wb (65,536 bf16)  ~19 MB
    u16* Qn = (u16*)d_ws;
    u16* Kn = Qn + (size_t)NBH * NSP * HD;
    u16* Vt = Kn + (size_t)NBH * NSP * HD;
    u16* X  = Vt + (size_t)NBH * NSP * HD;
    u16* Wb = X + (size_t)NB * NSP * NCH;

    wcast_kernel<<<dim3(64), dim3(256), 0, stream>>>(projw, Wb);
    prep_kernel<<<dim3(NSP / 256, NBH), dim3(256), 0, stream>>>(qkv, temp, Qn, Kn, Vt);
    attn_kernel<<<dim3(NSP / 64, NBH), dim3(128), 0, stream>>>(Qn, Kn, Vt, X);
    proj_kernel<<<dim3(NSP / 64, NCH / 64, NB), dim3(256), 0, stream>>>(Wb, X, projb, out);
}

// Round 3
// 165.137 us; speedup vs baseline: 1.2641x; 1.2641x over previous
//
#include <hip/hip_runtime.h>

typedef unsigned short u16;
typedef unsigned int   u32;
typedef __attribute__((ext_vector_type(8))) short short8;   // 8 bf16 = 4 VGPRs
typedef __attribute__((ext_vector_type(4))) float f32x4;

#define NB    4      // batch
#define NCH   256    // channels
#define NHD   8      // heads
#define HD    32     // head dim
#define NSP   2304   // H*W
#define NBH   32     // NB*NHD
#define NKT   36     // total 64-wide K tiles
#define KPW   18     // K tiles per wave (2-wave in-block k-split)

// round-to-nearest-even fp32 -> bf16 bits
__device__ __forceinline__ u16 f2bf(float f) {
    u32 u = __float_as_uint(f);
    u += 0x7FFFu + ((u >> 16) & 1u);
    return (u16)(u >> 16);
}
__device__ __forceinline__ u32 pack2(float a, float b) {
    return (u32)f2bf(a) | ((u32)f2bf(b) << 16);
}
// fast pack two fp32 -> bf16x2: hw cvt (RNE) if present, else 1-instr v_perm truncate.
// e in [1, 2.7]: truncation rel err <= 2^-9, and rowsum (via MFMA over the SAME
// packed values) stays exactly consistent with P, so softmax stays normalized.
__device__ __forceinline__ u32 pkfast(float a, float b) {
#if __has_builtin(__builtin_amdgcn_cvt_pk_bf16_f32)
    typedef __attribute__((ext_vector_type(2))) __bf16 bf2;
    union { bf2 v; u32 u; } cv;
    cv.v = __builtin_amdgcn_cvt_pk_bf16_f32(a, b);
    return cv.u;
#else
    return __builtin_amdgcn_perm(__float_as_uint(b), __float_as_uint(a), 0x07060302u);
#endif
}
__device__ __forceinline__ float fexp2(float x) {
#if __has_builtin(__builtin_amdgcn_exp2f)
    return __builtin_amdgcn_exp2f(x);
#else
    return exp2f(x);
#endif
}

// ---------------- proj_w -> bf16 ----------------
__global__ __launch_bounds__(256) void wcast_kernel(const float* __restrict__ w,
                                                    u16* __restrict__ wb) {
    int i = blockIdx.x * 256 + threadIdx.x;          // 16384 float4 chunks
    float4 v = ((const float4*)w)[i];
    ((uint2*)wb)[i] = make_uint2(pack2(v.x, v.y), pack2(v.z, v.w));
}

// ---------------- prep: normalize q,k (temp*log2e folded into q); v -> sigma-permuted tiles
// grid (NSP/64, 3 parts, NBH), block 64 (1 wave). part 0=q 1=k 2=v.
__global__ __launch_bounds__(64) void prep_kernel(
    const float* __restrict__ qkv, const float* __restrict__ temp,
    u16* __restrict__ Qn, u16* __restrict__ Kn, u16* __restrict__ Vp)
{
    const int p  = blockIdx.y;
    const int bh = blockIdx.z, b = bh >> 3, head = bh & 7;
    const int n  = blockIdx.x * 64 + threadIdx.x;
    const float* src = qkv + ((size_t)(b * 3 * NCH + p * NCH + head * HD)) * NSP + n;

    float v[HD];
#pragma unroll
    for (int d = 0; d < HD; ++d) v[d] = src[(size_t)d * NSP];

    if (p == 2) {
        // V tile layout: Vp[bh][kt][d*64 + c*32 + quad*8 + jj] where the value at
        // (c,quad,jj) is column kr = c*32 + (jj<4 ? quad*4+jj : 16+quad*4+jj-4).
        // This makes the attn vb fragment a single contiguous 16B load.
        const int loc = threadIdx.x, c = loc >> 5, r5 = loc & 31;
        const int qd  = (r5 < 16) ? (r5 >> 2) : ((r5 - 16) >> 2);
        const int jj  = (r5 < 16) ? (r5 & 3) : (4 + (r5 & 3));
        u16* dst = Vp + (size_t)bh * NSP * HD + (size_t)blockIdx.x * 2048 + c * 32 + qd * 8 + jj;
#pragma unroll
        for (int d = 0; d < HD; ++d) dst[d * 64] = f2bf(v[d]);
    } else {
        float s = 0.f;
#pragma unroll
        for (int d = 0; d < HD; ++d) s += v[d] * v[d];
        float sc = 1.f / fmaxf(sqrtf(s), 1e-12f);
        if (p == 0) sc *= temp[head] * 1.44269504088896f;   // fold temp*log2e into q
        u32 pk[HD / 2];
#pragma unroll
        for (int i = 0; i < HD / 2; ++i) pk[i] = pack2(v[2 * i] * sc, v[2 * i + 1] * sc);
        u16* dst = (p == 0 ? Qn : Kn) + ((size_t)bh * NSP + n) * HD;
#pragma unroll
        for (int i = 0; i < 4; ++i) ((uint4*)dst)[i] = ((const uint4*)pk)[i];
    }
}

// ---------------- flash attention, barrier-free K-loop ----------------
// block = 128 thr (2 waves), grid (NSP/32, NBH). Both waves own the SAME 32 q-rows;
// wave w covers k-tiles [w*18, w*18+18). Partials are linearly combinable
// (exp(relu)/sum softmax has no running max) -> one LDS combine at the end.
// S^T = K.Q; its C/D (col=q=l15, row=kr=quad*4+r) feeds PV directly as A-frag under
// k-permutation sigma; V B-frags come pre-permuted from global (prep). Rowsum via
// MFMA against an all-ones B-frag (no VALU adds, no shuffles).
__global__ __launch_bounds__(128) void attn_kernel(
    const u16* __restrict__ Qn, const u16* __restrict__ Kn,
    const u16* __restrict__ Vp, u16* __restrict__ X)
{
    __shared__ float cmb[64][25];   // wave1 partials: 16 O + 8 rs per lane (pad to 25)
    const int bh = blockIdx.y, b = bh >> 3, head = bh & 7;
    const int w = threadIdx.x >> 6, lane = threadIdx.x & 63;
    const int l15 = lane & 15, quad = lane >> 4;
    const int qbase = blockIdx.x * 32;

    const u16* Kg = Kn + (size_t)bh * NSP * HD + (size_t)w * KPW * 2048 + l15 * HD + quad * 8;
    const u16* Vg = Vp + (size_t)bh * NSP * HD + (size_t)w * KPW * 2048 + l15 * 64 + quad * 8;

    short8 qfrag[2];
#pragma unroll
    for (int t2 = 0; t2 < 2; ++t2)
        qfrag[t2] = *(const short8*)(Qn + ((size_t)bh * NSP + qbase + t2 * 16 + l15) * HD + quad * 8);

    const short one = (short)0x3F80;   // bf16 1.0
    const short8 vones = {one, one, one, one, one, one, one, one};

    f32x4 oacc[2][2] = {{{0,0,0,0},{0,0,0,0}},{{0,0,0,0},{0,0,0,0}}};
    f32x4 rsac[2]    = {{0,0,0,0},{0,0,0,0}};

    for (int kt = 0; kt < KPW; ++kt) {
        short8 ka[4], vbf[2][2];
#pragma unroll
        for (int i = 0; i < 4; ++i)
            ka[i] = *(const short8*)(Kg + i * 512);       // K rows i*16+l15, 1KB/instr coalesced
#pragma unroll
        for (int c = 0; c < 2; ++c)
#pragma unroll
            for (int h = 0; h < 2; ++h)
                vbf[c][h] = *(const short8*)(Vg + h * 1024 + c * 32);   // sigma-permuted
        Kg += 2048; Vg += 2048;

#pragma unroll
        for (int t2 = 0; t2 < 2; ++t2) {
            f32x4 sf[4];
#pragma unroll
            for (int i = 0; i < 4; ++i)
                sf[i] = __builtin_amdgcn_mfma_f32_16x16x32_bf16(ka[i], qfrag[t2], (f32x4){0.f,0.f,0.f,0.f}, 0, 0, 0);
            u32 pk[4][2];
#pragma unroll
            for (int i = 0; i < 4; ++i) {
                pk[i][0] = pkfast(fexp2(fmaxf(sf[i][0], 0.f)), fexp2(fmaxf(sf[i][1], 0.f)));
                pk[i][1] = pkfast(fexp2(fmaxf(sf[i][2], 0.f)), fexp2(fmaxf(sf[i][3], 0.f)));
            }
#pragma unroll
            for (int c = 0; c < 2; ++c) {
                union { short8 s; u32 u[4]; } pa;
                pa.u[0] = pk[2 * c][0];     pa.u[1] = pk[2 * c][1];
                pa.u[2] = pk[2 * c + 1][0]; pa.u[3] = pk[2 * c + 1][1];
                oacc[t2][0] = __builtin_amdgcn_mfma_f32_16x16x32_bf16(pa.s, vbf[c][0], oacc[t2][0], 0, 0, 0);
                oacc[t2][1] = __builtin_amdgcn_mfma_f32_16x16x32_bf16(pa.s, vbf[c][1], oacc[t2][1], 0, 0, 0);
                rsac[t2]    = __builtin_amdgcn_mfma_f32_16x16x32_bf16(pa.s, vones,     rsac[t2],    0, 0, 0);
            }
        }
    }

    // combine the two k-half partials through LDS (single barrier in the kernel)
    if (w == 1) {
#pragma unroll
        for (int t2 = 0; t2 < 2; ++t2) {
#pragma unroll
            for (int h = 0; h < 2; ++h)
#pragma unroll
                for (int r = 0; r < 4; ++r) cmb[lane][t2 * 8 + h * 4 + r] = oacc[t2][h][r];
#pragma unroll
            for (int r = 0; r < 4; ++r) cmb[lane][16 + t2 * 4 + r] = rsac[t2][r];
        }
    }
    __syncthreads();
    if (w == 0) {
        u16* Xb = X + (size_t)b * NSP * NCH + head * HD;
#pragma unroll
        for (int t2 = 0; t2 < 2; ++t2) {
            float inv[4];
#pragma unroll
            for (int r = 0; r < 4; ++r)
                inv[r] = 1.f / (rsac[t2][r] + cmb[lane][16 + t2 * 4 + r]);
#pragma unroll
            for (int r = 0; r < 4; ++r) {
                u16* row = Xb + (size_t)(qbase + t2 * 16 + quad * 4 + r) * NCH;
                row[l15]      = f2bf((oacc[t2][0][r] + cmb[lane][t2 * 8 + r])     * inv[r]);
                row[16 + l15] = f2bf((oacc[t2][1][r] + cmb[lane][t2 * 8 + 4 + r]) * inv[r]);
            }
        }
    }
}

// ---------------- 1x1 conv: out[b,o,n] = sum_c W[o,c] X[b,n,c] + bias[o] ----------------
// grid (NSP/32, NCH/16, NB), block 64 (1 wave): 16 o x 32 n per wave, operands from L2.
__global__ __launch_bounds__(64) void proj_kernel(
    const u16* __restrict__ Wb, const u16* __restrict__ X,
    const float* __restrict__ bias, float* __restrict__ out)
{
    const int b = blockIdx.z;
    const int lane = threadIdx.x;
    const int l15 = lane & 15, quad = lane >> 4;
    const int obase = blockIdx.y * 16;
    const int nbase = blockIdx.x * 32;

    const u16* wrow = Wb + (size_t)(obase + l15) * NCH + quad * 8;
    const u16* xrow = X + ((size_t)b * NSP + nbase + l15) * NCH + quad * 8;

    f32x4 acc[2] = {{0,0,0,0},{0,0,0,0}};
#pragma unroll
    for (int ks = 0; ks < 8; ++ks) {
        const short8 af = *(const short8*)(wrow + ks * 32);
        acc[0] = __builtin_amdgcn_mfma_f32_16x16x32_bf16(af, *(const short8*)(xrow + ks * 32), acc[0], 0, 0, 0);
        acc[1] = __builtin_amdgcn_mfma_f32_16x16x32_bf16(af, *(const short8*)(xrow + (size_t)16 * NCH + ks * 32), acc[1], 0, 0, 0);
    }
#pragma unroll
    for (int r = 0; r < 4; ++r) {
        const int o = obase + quad * 4 + r;
        const float bo = bias[o];
        float* orow = out + ((size_t)b * NCH + o) * NSP + nbase;
        orow[l15]      = acc[0][r] + bo;
        orow[16 + l15] = acc[1][r] + bo;
    }
}

extern "C" void kernel_launch(void* const* d_in, const int* in_sizes, int n_in,
                              void* d_out, int out_size, void* d_ws, size_t ws_size,
                              hipStream_t stream) {
    const float* qkv   = (const float*)d_in[0];
    const float* temp  = (const float*)d_in[1];
    const float* projw = (const float*)d_in[2];
    const float* projb = (const float*)d_in[3];
    float* out = (float*)d_out;

    // workspace: Qn | Kn | Vp | X (each 2,359,296 bf16) | Wb (65,536 bf16)  ~19 MB
    u16* Qn = (u16*)d_ws;
    u16* Kn = Qn + (size_t)NBH * NSP * HD;
    u16* Vp = Kn + (size_t)NBH * NSP * HD;
    u16* X  = Vp + (size_t)NBH * NSP * HD;
    u16* Wb = X + (size_t)NB * NSP * NCH;

    wcast_kernel<<<dim3(64), dim3(256), 0, stream>>>(projw, Wb);
    prep_kernel<<<dim3(NSP / 64, 3, NBH), dim3(64), 0, stream>>>(qkv, temp, Qn, Kn, Vp);
    attn_kernel<<<dim3(NSP / 32, NBH), dim3(128), 0, stream>>>(Qn, Kn, Vp, X);
    proj_kernel<<<dim3(NSP / 32, NCH / 16, NB), dim3(64), 0, stream>>>(Wb, X, projb, out);
}

// Round 4
// 159.285 us; speedup vs baseline: 1.3105x; 1.0367x over previous
//
#include <hip/hip_runtime.h>

typedef unsigned short u16;
typedef unsigned int   u32;
typedef __attribute__((ext_vector_type(8))) short short8;   // 8 bf16 = 4 VGPRs
typedef __attribute__((ext_vector_type(4))) float f32x4;

#define NB    4      // batch
#define NCH   256    // channels
#define NHD   8      // heads
#define HD    32     // head dim
#define NSP   2304   // H*W
#define NBH   32     // NB*NHD
#define NKT   36     // total 64-wide K tiles
#define KPW   9      // K tiles per wave (4-wave in-block k-split)

// round-to-nearest-even fp32 -> bf16 bits
__device__ __forceinline__ u16 f2bf(float f) {
    u32 u = __float_as_uint(f);
    u += 0x7FFFu + ((u >> 16) & 1u);
    return (u16)(u >> 16);
}
__device__ __forceinline__ u32 pack2(float a, float b) {
    return (u32)f2bf(a) | ((u32)f2bf(b) << 16);
}
// fast pack two fp32 -> bf16x2: hw cvt (RNE) if present, else 1-instr v_perm truncate.
// e in [1, 2.7]; rowsum (via MFMA over the SAME packed values) stays exactly
// consistent with P, so softmax stays normalized.
__device__ __forceinline__ u32 pkfast(float a, float b) {
#if __has_builtin(__builtin_amdgcn_cvt_pk_bf16_f32)
    typedef __attribute__((ext_vector_type(2))) __bf16 bf2;
    union { bf2 v; u32 u; } cv;
    cv.v = __builtin_amdgcn_cvt_pk_bf16_f32(a, b);
    return cv.u;
#else
    return __builtin_amdgcn_perm(__float_as_uint(b), __float_as_uint(a), 0x07060302u);
#endif
}
__device__ __forceinline__ float fexp2(float x) {
#if __has_builtin(__builtin_amdgcn_exp2f)
    return __builtin_amdgcn_exp2f(x);
#else
    return exp2f(x);
#endif
}

// ---------------- proj_w -> bf16 ----------------
__global__ __launch_bounds__(256) void wcast_kernel(const float* __restrict__ w,
                                                    u16* __restrict__ wb) {
    int i = blockIdx.x * 256 + threadIdx.x;          // 16384 float4 chunks
    float4 v = ((const float4*)w)[i];
    ((uint2*)wb)[i] = make_uint2(pack2(v.x, v.y), pack2(v.z, v.w));
}

// ---------------- prep: normalize q,k (temp*log2e folded into q); v -> sigma-permuted tiles
// grid (NSP/64, 3 parts, NBH), block 64 (1 wave). part 0=q 1=k 2=v.
__global__ __launch_bounds__(64) void prep_kernel(
    const float* __restrict__ qkv, const float* __restrict__ temp,
    u16* __restrict__ Qn, u16* __restrict__ Kn, u16* __restrict__ Vp)
{
    const int p  = blockIdx.y;
    const int bh = blockIdx.z, b = bh >> 3, head = bh & 7;
    const int n  = blockIdx.x * 64 + threadIdx.x;
    const float* src = qkv + ((size_t)(b * 3 * NCH + p * NCH + head * HD)) * NSP + n;

    float v[HD];
#pragma unroll
    for (int d = 0; d < HD; ++d) v[d] = src[(size_t)d * NSP];

    if (p == 2) {
        // V tile layout: Vp[bh][kt][d*64 + c*32 + quad*8 + jj]: value at (c,quad,jj)
        // is column kr = c*32 + (jj<4 ? quad*4+jj : 16+quad*4+jj-4) -> attn vb
        // fragment is one contiguous 16B load.
        const int loc = threadIdx.x, c = loc >> 5, r5 = loc & 31;
        const int qd  = (r5 < 16) ? (r5 >> 2) : ((r5 - 16) >> 2);
        const int jj  = (r5 < 16) ? (r5 & 3) : (4 + (r5 & 3));
        u16* dst = Vp + (size_t)bh * NSP * HD + (size_t)blockIdx.x * 2048 + c * 32 + qd * 8 + jj;
#pragma unroll
        for (int d = 0; d < HD; ++d) dst[d * 64] = f2bf(v[d]);
    } else {
        float s = 0.f;
#pragma unroll
        for (int d = 0; d < HD; ++d) s += v[d] * v[d];
        float sc = 1.f / fmaxf(sqrtf(s), 1e-12f);
        if (p == 0) sc *= temp[head] * 1.44269504088896f;   // fold temp*log2e into q
        u32 pk[HD / 2];
#pragma unroll
        for (int i = 0; i < HD / 2; ++i) pk[i] = pack2(v[2 * i] * sc, v[2 * i + 1] * sc);
        u16* dst = (p == 0 ? Qn : Kn) + ((size_t)bh * NSP + n) * HD;
#pragma unroll
        for (int i = 0; i < 4; ++i) ((uint4*)dst)[i] = ((const uint4*)pk)[i];
    }
}

// ---------------- flash attention: barrier-free K-loop, reg-prefetch, 4-way k-split --------
// block = 256 thr (4 waves), grid (NBH, NSP/32). blockIdx.x = bh so all q-blocks of a
// bh share one XCD (linear%8 == bh%8) -> K/V L2-resident (1.2 MB/XCD).
// All 4 waves own the SAME 32 q-rows; wave w covers k-tiles [w*9, w*9+9). Partials
// combine linearly (exp(relu)/sum softmax: no running max) -> one epilogue barrier.
// S^T = K.Q; C/D (col=q=l15, row=kr=quad*4+r) feeds PV directly as A-frag under
// k-permutation sigma; V B-frags come sigma-permuted from prep. Rowsum via MFMA
// against all-ones B. Next tile's K/V prefetched into registers during compute.
__global__ __launch_bounds__(256, 4) void attn_kernel(
    const u16* __restrict__ Qn, const u16* __restrict__ Kn,
    const u16* __restrict__ Vp, u16* __restrict__ X)
{
    __shared__ float cmb[3][64][25];   // waves 1-3 partials: 16 O + 8 rs per lane (pad 25)
    const int bh = blockIdx.x, b = bh >> 3, head = bh & 7;
    const int w = threadIdx.x >> 6, lane = threadIdx.x & 63;
    const int l15 = lane & 15, quad = lane >> 4;
    const int qbase = blockIdx.y * 32;

    const u16* Kg = Kn + (size_t)bh * NSP * HD + (size_t)w * KPW * 2048 + l15 * HD + quad * 8;
    const u16* Vg = Vp + (size_t)bh * NSP * HD + (size_t)w * KPW * 2048 + l15 * 64 + quad * 8;

    short8 qfrag[2];
#pragma unroll
    for (int t2 = 0; t2 < 2; ++t2)
        qfrag[t2] = *(const short8*)(Qn + ((size_t)bh * NSP + qbase + t2 * 16 + l15) * HD + quad * 8);

    const short one = (short)0x3F80;   // bf16 1.0
    const short8 vones = {one, one, one, one, one, one, one, one};

    f32x4 oacc[2][2] = {{{0,0,0,0},{0,0,0,0}},{{0,0,0,0},{0,0,0,0}}};
    f32x4 rsac[2]    = {{0,0,0,0},{0,0,0,0}};

    // preload tile 0 into registers
    short8 ka[4], vb[2][2];
#pragma unroll
    for (int i = 0; i < 4; ++i) ka[i] = *(const short8*)(Kg + i * 512);
#pragma unroll
    for (int c = 0; c < 2; ++c)
#pragma unroll
        for (int h = 0; h < 2; ++h) vb[c][h] = *(const short8*)(Vg + h * 1024 + c * 32);

    for (int kt = 0; kt < KPW; ++kt) {
        // prefetch next tile while computing this one
        short8 kan[4], vbn[2][2];
        if (kt + 1 < KPW) {
            const u16* Kp2 = Kg + (size_t)(kt + 1) * 2048;
            const u16* Vp2 = Vg + (size_t)(kt + 1) * 2048;
#pragma unroll
            for (int i = 0; i < 4; ++i) kan[i] = *(const short8*)(Kp2 + i * 512);
#pragma unroll
            for (int c = 0; c < 2; ++c)
#pragma unroll
                for (int h = 0; h < 2; ++h) vbn[c][h] = *(const short8*)(Vp2 + h * 1024 + c * 32);
        }

#pragma unroll
        for (int t2 = 0; t2 < 2; ++t2) {
            f32x4 sf[4];
#pragma unroll
            for (int i = 0; i < 4; ++i)
                sf[i] = __builtin_amdgcn_mfma_f32_16x16x32_bf16(ka[i], qfrag[t2], (f32x4){0.f,0.f,0.f,0.f}, 0, 0, 0);
            u32 pk[4][2];
#pragma unroll
            for (int i = 0; i < 4; ++i) {
                pk[i][0] = pkfast(fexp2(fmaxf(sf[i][0], 0.f)), fexp2(fmaxf(sf[i][1], 0.f)));
                pk[i][1] = pkfast(fexp2(fmaxf(sf[i][2], 0.f)), fexp2(fmaxf(sf[i][3], 0.f)));
            }
#pragma unroll
            for (int c = 0; c < 2; ++c) {
                union { short8 s; u32 u[4]; } pa;
                pa.u[0] = pk[2 * c][0];     pa.u[1] = pk[2 * c][1];
                pa.u[2] = pk[2 * c + 1][0]; pa.u[3] = pk[2 * c + 1][1];
                oacc[t2][0] = __builtin_amdgcn_mfma_f32_16x16x32_bf16(pa.s, vb[c][0], oacc[t2][0], 0, 0, 0);
                oacc[t2][1] = __builtin_amdgcn_mfma_f32_16x16x32_bf16(pa.s, vb[c][1], oacc[t2][1], 0, 0, 0);
                rsac[t2]    = __builtin_amdgcn_mfma_f32_16x16x32_bf16(pa.s, vones,    rsac[t2],    0, 0, 0);
            }
        }

        if (kt + 1 < KPW) {
#pragma unroll
            for (int i = 0; i < 4; ++i) ka[i] = kan[i];
#pragma unroll
            for (int c = 0; c < 2; ++c)
#pragma unroll
                for (int h = 0; h < 2; ++h) vb[c][h] = vbn[c][h];
        }
    }

    // combine the four k-quarter partials through LDS (single barrier)
    if (w != 0) {
        float* dst = &cmb[w - 1][lane][0];
#pragma unroll
        for (int t2 = 0; t2 < 2; ++t2) {
#pragma unroll
            for (int h = 0; h < 2; ++h)
#pragma unroll
                for (int r = 0; r < 4; ++r) dst[t2 * 8 + h * 4 + r] = oacc[t2][h][r];
#pragma unroll
            for (int r = 0; r < 4; ++r) dst[16 + t2 * 4 + r] = rsac[t2][r];
        }
    }
    __syncthreads();
    if (w == 0) {
        u16* Xb = X + (size_t)b * NSP * NCH + head * HD;
#pragma unroll
        for (int t2 = 0; t2 < 2; ++t2) {
            float o0[4], o1[4], rsum[4];
#pragma unroll
            for (int r = 0; r < 4; ++r) {
                o0[r] = oacc[t2][0][r]; o1[r] = oacc[t2][1][r]; rsum[r] = rsac[t2][r];
            }
#pragma unroll
            for (int j = 0; j < 3; ++j) {
                const float* srcp = &cmb[j][lane][0];
#pragma unroll
                for (int r = 0; r < 4; ++r) {
                    o0[r]   += srcp[t2 * 8 + r];
                    o1[r]   += srcp[t2 * 8 + 4 + r];
                    rsum[r] += srcp[16 + t2 * 4 + r];
                }
            }
#pragma unroll
            for (int r = 0; r < 4; ++r) {
                const float inv = 1.f / rsum[r];
                u16* row = Xb + (size_t)(qbase + t2 * 16 + quad * 4 + r) * NCH;
                row[l15]      = f2bf(o0[r] * inv);
                row[16 + l15] = f2bf(o1[r] * inv);
            }
        }
    }
}

// ---------------- 1x1 conv: out[b,o,n] = sum_c W[o,c] X[b,n,c] + bias[o] ----------------
// grid (NSP/32, NCH/16, NB), block 64 (1 wave): 16 o x 32 n per wave, operands from L2.
__global__ __launch_bounds__(64) void proj_kernel(
    const u16* __restrict__ Wb, const u16* __restrict__ X,
    const float* __restrict__ bias, float* __restrict__ out)
{
    const int b = blockIdx.z;
    const int lane = threadIdx.x;
    const int l15 = lane & 15, quad = lane >> 4;
    const int obase = blockIdx.y * 16;
    const int nbase = blockIdx.x * 32;

    const u16* wrow = Wb + (size_t)(obase + l15) * NCH + quad * 8;
    const u16* xrow = X + ((size_t)b * NSP + nbase + l15) * NCH + quad * 8;

    f32x4 acc[2] = {{0,0,0,0},{0,0,0,0}};
#pragma unroll
    for (int ks = 0; ks < 8; ++ks) {
        const short8 af = *(const short8*)(wrow + ks * 32);
        acc[0] = __builtin_amdgcn_mfma_f32_16x16x32_bf16(af, *(const short8*)(xrow + ks * 32), acc[0], 0, 0, 0);
        acc[1] = __builtin_amdgcn_mfma_f32_16x16x32_bf16(af, *(const short8*)(xrow + (size_t)16 * NCH + ks * 32), acc[1], 0, 0, 0);
    }
#pragma unroll
    for (int r = 0; r < 4; ++r) {
        const int o = obase + quad * 4 + r;
        const float bo = bias[o];
        float* orow = out + ((size_t)b * NCH + o) * NSP + nbase;
        orow[l15]      = acc[0][r] + bo;
        orow[16 + l15] = acc[1][r] + bo;
    }
}

extern "C" void kernel_launch(void* const* d_in, const int* in_sizes, int n_in,
                              void* d_out, int out_size, void* d_ws, size_t ws_size,
                              hipStream_t stream) {
    const float* qkv   = (const float*)d_in[0];
    const float* temp  = (const float*)d_in[1];
    const float* projw = (const float*)d_in[2];
    const float* projb = (const float*)d_in[3];
    float* out = (float*)d_out;

    // workspace: Qn | Kn | Vp | X (each 2,359,296 bf16) | Wb (65,536 bf16)  ~19 MB
    u16* Qn = (u16*)d_ws;
    u16* Kn = Qn + (size_t)NBH * NSP * HD;
    u16* Vp = Kn + (size_t)NBH * NSP * HD;
    u16* X  = Vp + (size_t)NBH * NSP * HD;
    u16* Wb = X + (size_t)NB * NSP * NCH;

    wcast_kernel<<<dim3(64), dim3(256), 0, stream>>>(projw, Wb);
    prep_kernel<<<dim3(NSP / 64, 3, NBH), dim3(64), 0, stream>>>(qkv, temp, Qn, Kn, Vp);
    attn_kernel<<<dim3(NBH, NSP / 32), dim3(256), 0, stream>>>(Qn, Kn, Vp, X);
    proj_kernel<<<dim3(NSP / 32, NCH / 16, NB), dim3(64), 0, stream>>>(Wb, X, projb, out);
}

// Round 5
// 147.788 us; speedup vs baseline: 1.4125x; 1.0778x over previous
//
#include <hip/hip_runtime.h>

typedef unsigned short u16;
typedef unsigned int   u32;
typedef __attribute__((ext_vector_type(8))) short short8;   // 8 bf16 = 4 VGPRs
typedef __attribute__((ext_vector_type(4))) float f32x4;

#define NB    4      // batch
#define NCH   256    // channels
#define NHD   8      // heads
#define HD    32     // head dim
#define NSP   2304   // H*W
#define NBH   32     // NB*NHD
#define NKT   36     // total 64-wide K tiles
#define KPW   9      // K tiles per wave (4-wave in-block k-split)

// round-to-nearest-even fp32 -> bf16 bits
__device__ __forceinline__ u16 f2bf(float f) {
    u32 u = __float_as_uint(f);
    u += 0x7FFFu + ((u >> 16) & 1u);
    return (u16)(u >> 16);
}
__device__ __forceinline__ u32 pack2(float a, float b) {
    return (u32)f2bf(a) | ((u32)f2bf(b) << 16);
}
// fast pack two fp32 -> bf16x2: hw cvt (RNE) if present, else 1-instr v_perm truncate.
// e in [1, 2.7]; rowsum (MFMA over the SAME packed values) stays consistent with P.
__device__ __forceinline__ u32 pkfast(float a, float b) {
#if __has_builtin(__builtin_amdgcn_cvt_pk_bf16_f32)
    typedef __attribute__((ext_vector_type(2))) __bf16 bf2;
    union { bf2 v; u32 u; } cv;
    cv.v = __builtin_amdgcn_cvt_pk_bf16_f32(a, b);
    return cv.u;
#else
    return __builtin_amdgcn_perm(__float_as_uint(b), __float_as_uint(a), 0x07060302u);
#endif
}
__device__ __forceinline__ float fexp2(float x) {
#if __has_builtin(__builtin_amdgcn_exp2f)
    return __builtin_amdgcn_exp2f(x);
#else
    return exp2f(x);
#endif
}

// ---------------- prep: normalize q,k (temp*log2e folded into q); v -> sigma-permuted
// tiles; p==3 slice casts proj_w -> bf16. grid (NSP/256, 4, NBH), block 256.
__global__ __launch_bounds__(256) void prep_kernel(
    const float* __restrict__ qkv, const float* __restrict__ temp,
    const float* __restrict__ projw,
    u16* __restrict__ Qn, u16* __restrict__ Kn, u16* __restrict__ Vp,
    u16* __restrict__ Wb)
{
    const int p  = blockIdx.y;
    const int bh = blockIdx.z, b = bh >> 3, head = bh & 7;

    if (p == 3) {   // proj_w cast: 16384 float4 chunks spread over 9*32 blocks
        const int idx = (bh * (NSP / 256) + blockIdx.x) * 256 + threadIdx.x;
        if (idx < NCH * NCH / 4) {
            float4 v = ((const float4*)projw)[idx];
            ((uint2*)Wb)[idx] = make_uint2(pack2(v.x, v.y), pack2(v.z, v.w));
        }
        return;
    }

    const int n = blockIdx.x * 256 + threadIdx.x;
    const float* src = qkv + ((size_t)(b * 3 * NCH + p * NCH + head * HD)) * NSP + n;

    float v[HD];
#pragma unroll
    for (int d = 0; d < HD; ++d) v[d] = src[(size_t)d * NSP];

    if (p == 2) {
        // V tile layout: Vp[bh][kt][d*64 + c*32 + quad*8 + jj]: value at (c,quad,jj)
        // is column kr = c*32 + (jj<4 ? quad*4+jj : 16+quad*4+jj-4) -> attn vb
        // fragment is one contiguous 16B load.
        const int tile = n >> 6, loc = n & 63;
        const int c = loc >> 5, r5 = loc & 31;
        const int qd  = (r5 < 16) ? (r5 >> 2) : ((r5 - 16) >> 2);
        const int jj  = (r5 < 16) ? (r5 & 3) : (4 + (r5 & 3));
        u16* dst = Vp + (size_t)bh * NSP * HD + (size_t)tile * 2048 + c * 32 + qd * 8 + jj;
#pragma unroll
        for (int d = 0; d < HD; ++d) dst[d * 64] = f2bf(v[d]);
    } else {
        float s = 0.f;
#pragma unroll
        for (int d = 0; d < HD; ++d) s += v[d] * v[d];
        float sc = 1.f / fmaxf(sqrtf(s), 1e-12f);
        if (p == 0) sc *= temp[head] * 1.44269504088896f;   // fold temp*log2e into q
        u32 pk[HD / 2];
#pragma unroll
        for (int i = 0; i < HD / 2; ++i) pk[i] = pack2(v[2 * i] * sc, v[2 * i + 1] * sc);
        u16* dst = (p == 0 ? Qn : Kn) + ((size_t)bh * NSP + n) * HD;
#pragma unroll
        for (int i = 0; i < 4; ++i) ((uint4*)dst)[i] = ((const uint4*)pk)[i];
    }
}

// ---------------- flash attention: 64 q-rows/wave, 4-way k-split, barrier-free K-loop ----
// block = 256 thr (4 waves), grid (NBH, NSP/64). blockIdx.x = bh (linear%8 == bh%8) so
// all q-blocks of a bh share one XCD -> K/V L2-resident (1.2 MB/XCD).
// All 4 waves own the SAME 64 q-rows (4 q-tiles); wave w covers k-tiles [w*9,w*9+9).
// Partials combine linearly (exp(relu)/sum: no running max) -> one epilogue barrier;
// wave w reduces + writes q-tile t2==w (parallel epilogue).
// S^T = K.Q; C/D (col=q=l15, row=kr=quad*4+r) feeds PV directly as A-frag under
// k-permutation sigma; V B-frags come sigma-permuted from prep. Rowsum via MFMA
// against all-ones B. K prefetched 1 tile ahead; V consumed ~200cyc after issue.
__global__ __launch_bounds__(256) void attn_kernel(
    const u16* __restrict__ Qn, const u16* __restrict__ Kn,
    const u16* __restrict__ Vp, u16* __restrict__ X)
{
    __shared__ float cmb[4][64][49];   // [wave][lane][t2*12 + {8 O0,O1 | 4 rs}] pad 49
    const int bh = blockIdx.x, b = bh >> 3, head = bh & 7;
    const int w = threadIdx.x >> 6, lane = threadIdx.x & 63;
    const int l15 = lane & 15, quad = lane >> 4;
    const int qbase = blockIdx.y * 64;

    const u16* Kg = Kn + (size_t)bh * NSP * HD + (size_t)w * KPW * 2048 + l15 * HD + quad * 8;
    const u16* Vg = Vp + (size_t)bh * NSP * HD + (size_t)w * KPW * 2048 + l15 * 64 + quad * 8;

    short8 qf[4];
#pragma unroll
    for (int t2 = 0; t2 < 4; ++t2)
        qf[t2] = *(const short8*)(Qn + ((size_t)bh * NSP + qbase + t2 * 16 + l15) * HD + quad * 8);

    const short one = (short)0x3F80;   // bf16 1.0
    const short8 vones = {one, one, one, one, one, one, one, one};

    f32x4 oacc[4][2] = {{{0,0,0,0},{0,0,0,0}},{{0,0,0,0},{0,0,0,0}},
                        {{0,0,0,0},{0,0,0,0}},{{0,0,0,0},{0,0,0,0}}};
    f32x4 rsac[4]    = {{0,0,0,0},{0,0,0,0},{0,0,0,0},{0,0,0,0}};

    // preload K tile 0
    short8 ka[4];
#pragma unroll
    for (int i = 0; i < 4; ++i) ka[i] = *(const short8*)(Kg + i * 512);

    for (int kt = 0; kt < KPW; ++kt) {
        // V for THIS tile: consumed only after S-MFMA+exp chain (latency self-hiding)
        short8 vb[2][2];
#pragma unroll
        for (int c = 0; c < 2; ++c)
#pragma unroll
            for (int h = 0; h < 2; ++h)
                vb[c][h] = *(const short8*)(Vg + (size_t)kt * 2048 + h * 1024 + c * 32);
        // K for NEXT tile
        short8 kan[4];
        if (kt + 1 < KPW) {
            const u16* Kp2 = Kg + (size_t)(kt + 1) * 2048;
#pragma unroll
            for (int i = 0; i < 4; ++i) kan[i] = *(const short8*)(Kp2 + i * 512);
        }

#pragma unroll
        for (int t2 = 0; t2 < 4; ++t2) {
            f32x4 sf[4];
#pragma unroll
            for (int i = 0; i < 4; ++i)
                sf[i] = __builtin_amdgcn_mfma_f32_16x16x32_bf16(ka[i], qf[t2], (f32x4){0.f,0.f,0.f,0.f}, 0, 0, 0);
            u32 pk[4][2];
#pragma unroll
            for (int i = 0; i < 4; ++i) {
                pk[i][0] = pkfast(fexp2(fmaxf(sf[i][0], 0.f)), fexp2(fmaxf(sf[i][1], 0.f)));
                pk[i][1] = pkfast(fexp2(fmaxf(sf[i][2], 0.f)), fexp2(fmaxf(sf[i][3], 0.f)));
            }
#pragma unroll
            for (int c = 0; c < 2; ++c) {
                union { short8 s; u32 u[4]; } pa;
                pa.u[0] = pk[2 * c][0];     pa.u[1] = pk[2 * c][1];
                pa.u[2] = pk[2 * c + 1][0]; pa.u[3] = pk[2 * c + 1][1];
                oacc[t2][0] = __builtin_amdgcn_mfma_f32_16x16x32_bf16(pa.s, vb[c][0], oacc[t2][0], 0, 0, 0);
                oacc[t2][1] = __builtin_amdgcn_mfma_f32_16x16x32_bf16(pa.s, vb[c][1], oacc[t2][1], 0, 0, 0);
                rsac[t2]    = __builtin_amdgcn_mfma_f32_16x16x32_bf16(pa.s, vones,    rsac[t2],    0, 0, 0);
            }
        }

        if (kt + 1 < KPW) {
#pragma unroll
            for (int i = 0; i < 4; ++i) ka[i] = kan[i];
        }
    }

    // publish all partials; wave w reduces + writes q-tile t2 == w
    {
        float* my = &cmb[w][lane][0];
#pragma unroll
        for (int t2 = 0; t2 < 4; ++t2) {
#pragma unroll
            for (int h = 0; h < 2; ++h)
#pragma unroll
                for (int r = 0; r < 4; ++r) my[t2 * 12 + h * 4 + r] = oacc[t2][h][r];
#pragma unroll
            for (int r = 0; r < 4; ++r) my[t2 * 12 + 8 + r] = rsac[t2][r];
        }
    }
    __syncthreads();
    {
        const int t2 = w;
        float o0[4] = {0,0,0,0}, o1[4] = {0,0,0,0}, rsum[4] = {0,0,0,0};
#pragma unroll
        for (int j = 0; j < 4; ++j) {
            const float* srcp = &cmb[j][lane][t2 * 12];
#pragma unroll
            for (int r = 0; r < 4; ++r) {
                o0[r]   += srcp[r];
                o1[r]   += srcp[4 + r];
                rsum[r] += srcp[8 + r];
            }
        }
        u16* Xb = X + (size_t)b * NSP * NCH + head * HD;
#pragma unroll
        for (int r = 0; r < 4; ++r) {
            const float inv = 1.f / rsum[r];
            u16* row = Xb + (size_t)(qbase + t2 * 16 + quad * 4 + r) * NCH;
            row[l15]      = f2bf(o0[r] * inv);
            row[16 + l15] = f2bf(o1[r] * inv);
        }
    }
}

// ---------------- 1x1 conv: out[b,o,n] = sum_c W[o,c] X[b,n,c] + bias[o] ----------------
// grid (NSP/32, NCH/16, NB), block 64 (1 wave): 16 o x 32 n per wave, operands from L2.
__global__ __launch_bounds__(64) void proj_kernel(
    const u16* __restrict__ Wb, const u16* __restrict__ X,
    const float* __restrict__ bias, float* __restrict__ out)
{
    const int b = blockIdx.z;
    const int lane = threadIdx.x;
    const int l15 = lane & 15, quad = lane >> 4;
    const int obase = blockIdx.y * 16;
    const int nbase = blockIdx.x * 32;

    const u16* wrow = Wb + (size_t)(obase + l15) * NCH + quad * 8;
    const u16* xrow = X + ((size_t)b * NSP + nbase + l15) * NCH + quad * 8;

    f32x4 acc[2] = {{0,0,0,0},{0,0,0,0}};
#pragma unroll
    for (int ks = 0; ks < 8; ++ks) {
        const short8 af = *(const short8*)(wrow + ks * 32);
        acc[0] = __builtin_amdgcn_mfma_f32_16x16x32_bf16(af, *(const short8*)(xrow + ks * 32), acc[0], 0, 0, 0);
        acc[1] = __builtin_amdgcn_mfma_f32_16x16x32_bf16(af, *(const short8*)(xrow + (size_t)16 * NCH + ks * 32), acc[1], 0, 0, 0);
    }
#pragma unroll
    for (int r = 0; r < 4; ++r) {
        const int o = obase + quad * 4 + r;
        const float bo = bias[o];
        float* orow = out + ((size_t)b * NCH + o) * NSP + nbase;
        orow[l15]      = acc[0][r] + bo;
        orow[16 + l15] = acc[1][r] + bo;
    }
}

extern "C" void kernel_launch(void* const* d_in, const int* in_sizes, int n_in,
                              void* d_out, int out_size, void* d_ws, size_t ws_size,
                              hipStream_t stream) {
    const float* qkv   = (const float*)d_in[0];
    const float* temp  = (const float*)d_in[1];
    const float* projw = (const float*)d_in[2];
    const float* projb = (const float*)d_in[3];
    float* out = (float*)d_out;

    // workspace: Qn | Kn | Vp | X (each 2,359,296 bf16) | Wb (65,536 bf16)  ~19 MB
    u16* Qn = (u16*)d_ws;
    u16* Kn = Qn + (size_t)NBH * NSP * HD;
    u16* Vp = Kn + (size_t)NBH * NSP * HD;
    u16* X  = Vp + (size_t)NBH * NSP * HD;
    u16* Wb = X + (size_t)NB * NSP * NCH;

    prep_kernel<<<dim3(NSP / 256, 4, NBH), dim3(256), 0, stream>>>(qkv, temp, projw, Qn, Kn, Vp, Wb);
    attn_kernel<<<dim3(NBH, NSP / 64), dim3(256), 0, stream>>>(Qn, Kn, Vp, X);
    proj_kernel<<<dim3(NSP / 32, NCH / 16, NB), dim3(64), 0, stream>>>(Wb, X, projb, out);
}